// Round 1
// baseline (3574.384 us; speedup 1.0000x reference)
//
#include <hip/hip_runtime.h>
#include <float.h>

#define DIM 512
#define MT 64
#define NT 64
#define KT 32
#define NSPLIT 64
#define NUM_CLASSES 1000

// ---------------- Kernel 1: 1/||x_n|| ----------------
__global__ __launch_bounds__(256) void rnorm_kernel(const float* __restrict__ x,
                                                    float* __restrict__ rnorm, int N) {
  int row = blockIdx.x * 4 + (threadIdx.x >> 6);
  int lane = threadIdx.x & 63;
  if (row >= N) return;
  const float4* p = (const float4*)(x + (size_t)row * DIM);
  float4 a = p[lane];
  float4 b = p[lane + 64];
  float s = a.x*a.x + a.y*a.y + a.z*a.z + a.w*a.w
          + b.x*b.x + b.y*b.y + b.z*b.z + b.w*b.w;
  #pragma unroll
  for (int off = 32; off > 0; off >>= 1) s += __shfl_down(s, off, 64);
  if (lane == 0) rnorm[row] = 1.0f / fmaxf(sqrtf(s), 1e-12f);
}

// ---------------- Kernel 2: tiled dot + per-split argmax ----------------
// Block: 256 threads. Tile: MT=64 queries x NT=64 candidates, K staged in KT=32 chunks.
// grid.x = M/MT (32), grid.y = NSPLIT (64). Each block scans its n-split, keeps
// per-thread best-of-4-queries, then reduces across the 16 threads sharing a query.
__global__ __launch_bounds__(256) void nn_argmax_kernel(
    const float* __restrict__ x, const float* __restrict__ q,
    const float* __restrict__ rnorm,
    float* __restrict__ pval, int* __restrict__ pidx,
    int N, int nPerSplit) {
  __shared__ float qs[KT][MT];
  __shared__ float xs[KT][NT];

  const int tid = threadIdx.x;
  const int tx = tid & 15;   // candidate group (4 each -> NT=64)
  const int ty = tid >> 4;   // query group (4 each -> MT=64)
  const int m0 = blockIdx.x * MT;
  const int ns = blockIdx.y;
  const int nStart = ns * nPerSplit;
  const int nEnd   = min(nStart + nPerSplit, N);

  float best[4];
  int   bidx[4];
  #pragma unroll
  for (int i = 0; i < 4; ++i) { best[i] = -FLT_MAX; bidx[i] = 0; }

  for (int n0 = nStart; n0 < nEnd; n0 += NT) {
    float acc[4][4];
    #pragma unroll
    for (int i = 0; i < 4; ++i)
      #pragma unroll
      for (int j = 0; j < 4; ++j) acc[i][j] = 0.0f;

    for (int k0 = 0; k0 < DIM; k0 += KT) {
      __syncthreads();  // protect LDS from previous iteration's readers
      // Stage q-tile and x-tile, transposed: [KT][64]. 512 float4 per tile.
      #pragma unroll
      for (int r = 0; r < 2; ++r) {
        int idx = tid + r * 256;        // 0..511
        int mm  = idx >> 3;             // 0..63
        int kk  = (idx & 7) * 4;        // 0,4,...,28
        float4 v = *(const float4*)(q + (size_t)(m0 + mm) * DIM + k0 + kk);
        qs[kk + 0][mm] = v.x; qs[kk + 1][mm] = v.y;
        qs[kk + 2][mm] = v.z; qs[kk + 3][mm] = v.w;
        int nn = n0 + mm;
        float4 w = make_float4(0.f, 0.f, 0.f, 0.f);
        if (nn < nEnd) w = *(const float4*)(x + (size_t)nn * DIM + k0 + kk);
        xs[kk + 0][mm] = w.x; xs[kk + 1][mm] = w.y;
        xs[kk + 2][mm] = w.z; xs[kk + 3][mm] = w.w;
      }
      __syncthreads();

      #pragma unroll
      for (int k = 0; k < KT; ++k) {
        float4 qa = *(const float4*)&qs[k][ty * 4];
        float4 xa = *(const float4*)&xs[k][tx * 4];
        float qv[4] = {qa.x, qa.y, qa.z, qa.w};
        float xv[4] = {xa.x, xa.y, xa.z, xa.w};
        #pragma unroll
        for (int i = 0; i < 4; ++i)
          #pragma unroll
          for (int j = 0; j < 4; ++j) acc[i][j] = fmaf(qv[i], xv[j], acc[i][j]);
      }
    }

    // Fold 1/||x_n|| and update per-thread argmax (ascending n => '>' keeps lowest idx).
    #pragma unroll
    for (int j = 0; j < 4; ++j) {
      int n = n0 + tx * 4 + j;
      if (n < nEnd) {
        float rn = rnorm[n];
        #pragma unroll
        for (int i = 0; i < 4; ++i) {
          float v = acc[i][j] * rn;
          if (v > best[i]) { best[i] = v; bidx[i] = n; }
        }
      }
    }
  }

  // Cross-thread reduce: 16 threads (tx) share each query row. Reuse qs/xs as scratch.
  __syncthreads();
  float* rvals = &qs[0][0];       // 64*17 <= 2048 floats
  int*   ridx  = (int*)&xs[0][0]; // 64*17 <= 2048 ints
  #pragma unroll
  for (int i = 0; i < 4; ++i) {
    int m = ty * 4 + i;
    rvals[m * 17 + tx] = best[i];
    ridx [m * 17 + tx] = bidx[i];
  }
  __syncthreads();
  if (tid < MT) {
    int m = tid;
    float bv = -FLT_MAX; int bi = 0;
    #pragma unroll
    for (int t = 0; t < 16; ++t) {
      float v = rvals[m * 17 + t];
      int   i = ridx [m * 17 + t];
      if (v > bv || (v == bv && i < bi)) { bv = v; bi = i; }
    }
    pval[(size_t)(m0 + m) * NSPLIT + ns] = bv;
    pidx[(size_t)(m0 + m) * NSPLIT + ns] = bi;
  }
}

// ---------------- Kernel 3: reduce partials, one-hot write ----------------
__global__ __launch_bounds__(256) void finalize_kernel(
    const float* __restrict__ pval, const int* __restrict__ pidx,
    const int* __restrict__ y, int* __restrict__ out) {
  int m = blockIdx.x;
  int tid = threadIdx.x;
  __shared__ int s_label;
  if (tid < 64) {
    float v = pval[(size_t)m * NSPLIT + tid];
    int   i = pidx[(size_t)m * NSPLIT + tid];
    #pragma unroll
    for (int off = 32; off > 0; off >>= 1) {
      float ov = __shfl_down(v, off, 64);
      int   oi = __shfl_down(i, off, 64);
      if (ov > v || (ov == v && oi < i)) { v = ov; i = oi; }
    }
    if (tid == 0) s_label = y[i];
  }
  __syncthreads();
  int label = s_label;
  for (int c = tid; c < NUM_CLASSES; c += 256)
    out[(size_t)m * NUM_CLASSES + c] = (c == label) ? 1 : 0;
}

extern "C" void kernel_launch(void* const* d_in, const int* in_sizes, int n_in,
                              void* d_out, int out_size, void* d_ws, size_t ws_size,
                              hipStream_t stream) {
  const float* x = (const float*)d_in[0];   // [N, 512]
  const int*   y = (const int*)d_in[1];     // [N]
  const float* q = (const float*)d_in[2];   // [M, 512]
  int N = in_sizes[0] / DIM;                // 100000
  int M = in_sizes[2] / DIM;                // 2048
  int* out = (int*)d_out;

  // Workspace layout: rnorm (512 KB) | pval (M*64 f32) | pidx (M*64 i32)
  float* rnorm = (float*)d_ws;
  float* pval  = (float*)((char*)d_ws + (1 << 19));
  int*   pidx  = (int*)  ((char*)d_ws + (1 << 19) + (size_t)M * NSPLIT * sizeof(float));

  rnorm_kernel<<<(N + 3) / 4, 256, 0, stream>>>(x, rnorm, N);

  int nPerSplit = (N + NSPLIT - 1) / NSPLIT;  // 1563
  dim3 grid(M / MT, NSPLIT);
  nn_argmax_kernel<<<grid, 256, 0, stream>>>(x, q, rnorm, pval, pidx, N, nPerSplit);

  finalize_kernel<<<M, 256, 0, stream>>>(pval, pidx, y, out);
}

// Round 3
// 922.466 us; speedup vs baseline: 3.8748x; 3.8748x over previous
//
#include <hip/hip_runtime.h>
#include <float.h>
#include <stdint.h>

#define DIM 512
#define BM 128
#define BN 128
#define BK 32
#define NSPLIT 64
#define NUM_CLASSES 1000
#define MARGIN 1e-3f

typedef unsigned short ushort_t;
typedef __attribute__((ext_vector_type(4))) float fvec4;
typedef __attribute__((ext_vector_type(8))) __bf16 bvec8;
typedef __attribute__((ext_vector_type(4))) int ivec4;

#define AS1 __attribute__((address_space(1)))
#define AS3 __attribute__((address_space(3)))

__device__ inline ushort_t bf16_rne(float f) {
  uint32_t u = __builtin_bit_cast(uint32_t, f);
  uint32_t r = u + 0x7fffu + ((u >> 16) & 1u);
  return (ushort_t)(r >> 16);
}

// ---------- prep: rnorm + split f32 -> (hi, lo) bf16 planes ----------
__global__ __launch_bounds__(256) void prep_split(
    const float* __restrict__ src, float* __restrict__ rnorm_out,
    ushort_t* __restrict__ hi, ushort_t* __restrict__ lo,
    int rows, int scale) {
  int row = blockIdx.x * 4 + (threadIdx.x >> 6);
  int l = threadIdx.x & 63;
  if (row >= rows) return;
  const float4* p = (const float4*)(src + (size_t)row * DIM);
  float4 a = p[l * 2], b = p[l * 2 + 1];
  float rn = 1.0f;
  if (scale) {
    float s = a.x*a.x + a.y*a.y + a.z*a.z + a.w*a.w
            + b.x*b.x + b.y*b.y + b.z*b.z + b.w*b.w;
    #pragma unroll
    for (int off = 1; off < 64; off <<= 1) s += __shfl_xor(s, off, 64);
    rn = 1.0f / fmaxf(sqrtf(s), 1e-12f);
    if (rnorm_out && l == 0) rnorm_out[row] = rn;
  }
  if (!hi) return;
  float v[8] = {a.x*rn, a.y*rn, a.z*rn, a.w*rn, b.x*rn, b.y*rn, b.z*rn, b.w*rn};
  ivec4 hw, lw;
  #pragma unroll
  for (int t = 0; t < 4; ++t) {
    ushort_t h0 = bf16_rne(v[2*t]), h1 = bf16_rne(v[2*t+1]);
    float h0f = __builtin_bit_cast(float, (uint32_t)h0 << 16);
    float h1f = __builtin_bit_cast(float, (uint32_t)h1 << 16);
    ushort_t l0 = bf16_rne(v[2*t] - h0f), l1 = bf16_rne(v[2*t+1] - h1f);
    hw[t] = (int)((uint32_t)h0 | ((uint32_t)h1 << 16));
    lw[t] = (int)((uint32_t)l0 | ((uint32_t)l1 << 16));
  }
  *(ivec4*)(hi + (size_t)row * DIM + l * 8) = hw;
  *(ivec4*)(lo + (size_t)row * DIM + l * 8) = lw;
}

// ---------- GEMM+argmax: split-bf16 MFMA, per-(query,split,wn) top-2 ----------
// LDS layout (bf16, lane-linear fragment blobs of 1KB = 16 rows x 32 k):
//   byte(row,k) = region + (row>>4)*1024 + (k>>3)*256 + (row&15)*16 + (k&7)*2
// Fragment read (lane l: row=l&15, k=8*(l>>4)+j) = base + l*16 -> conflict-free
// ds_read_b128, and matches global_load_lds's base + lane*16 destination rule.
// NOTE: waves wn=0 and wn=1 cover DISJOINT candidate halves of each tile, so
// partials are written per-(m, split, wn) -- R2's shared slot was a race.
template <bool PRE>
__global__ __launch_bounds__(256, 2) void nn_mfma(
    const ushort_t* __restrict__ qh, const ushort_t* __restrict__ ql,
    const ushort_t* __restrict__ xh, const ushort_t* __restrict__ xl,
    const float* __restrict__ qf, const float* __restrict__ xf,
    const float* __restrict__ rnorm,
    float* __restrict__ pval2, int* __restrict__ pidx2,
    int N, int nPerSplit) {
  __shared__ __align__(1024) char smem[32768];  // AH|AL|BH|BL, 8KB each
  const int tid = threadIdx.x;
  const int l = tid & 63, w = tid >> 6;
  const int wm = w >> 1, wn = w & 1;
  const int lrow = l & 15, lk8 = (l >> 4) * 8;
  const int split = blockIdx.x;
  const int m0 = blockIdx.y * BM;
  const int nStart = split * nPerSplit;
  const int nEnd = min(nStart + nPerSplit, N);

  float B1[16], B2[16]; int I1[16], I2[16];
  #pragma unroll
  for (int s = 0; s < 16; ++s) { B1[s] = -FLT_MAX; B2[s] = -FLT_MAX; I1[s] = 0; I2[s] = 0; }

  const fvec4 zero4 = {0.f, 0.f, 0.f, 0.f};

  #pragma unroll 1
  for (int n0 = nStart; n0 < nEnd; n0 += BN) {
    fvec4 acc[4][4];
    #pragma unroll
    for (int i = 0; i < 4; ++i)
      #pragma unroll
      for (int j = 0; j < 4; ++j) acc[i][j] = zero4;

    #pragma unroll 1
    for (int k0 = 0; k0 < DIM; k0 += BK) {
      if (PRE) {
        #pragma unroll
        for (int b = 0; b < 2; ++b) {
          int f = 2 * w + b;
          int arow = m0 + 16 * f + lrow;
          int brow = min(n0 + 16 * f + lrow, N - 1);
          size_t aoff = (size_t)arow * DIM + k0 + lk8;
          size_t boff = (size_t)brow * DIM + k0 + lk8;
          __builtin_amdgcn_global_load_lds((const AS1 int*)(qh + aoff), (AS3 int*)(smem +     0 + f * 1024), 16, 0, 0);
          __builtin_amdgcn_global_load_lds((const AS1 int*)(ql + aoff), (AS3 int*)(smem +  8192 + f * 1024), 16, 0, 0);
          __builtin_amdgcn_global_load_lds((const AS1 int*)(xh + boff), (AS3 int*)(smem + 16384 + f * 1024), 16, 0, 0);
          __builtin_amdgcn_global_load_lds((const AS1 int*)(xl + boff), (AS3 int*)(smem + 24576 + f * 1024), 16, 0, 0);
        }
      } else {
        #pragma unroll
        for (int u = 0; u < 2; ++u) {
          int unit = tid + 256 * u;            // 0..511
          int row = unit & 127, kg = unit >> 7;
          int base = (row >> 4) * 1024 + kg * 256 + (row & 15) * 16;
          {
            const float* s0 = qf + (size_t)(m0 + row) * DIM + k0 + kg * 8;
            float4 a0 = *(const float4*)s0, a1 = *(const float4*)(s0 + 4);
            float vv[8] = {a0.x,a0.y,a0.z,a0.w,a1.x,a1.y,a1.z,a1.w};
            ivec4 hw, lw;
            #pragma unroll
            for (int t = 0; t < 4; ++t) {
              ushort_t h0 = bf16_rne(vv[2*t]), h1 = bf16_rne(vv[2*t+1]);
              float h0f = __builtin_bit_cast(float, (uint32_t)h0 << 16);
              float h1f = __builtin_bit_cast(float, (uint32_t)h1 << 16);
              ushort_t l0 = bf16_rne(vv[2*t]-h0f), l1 = bf16_rne(vv[2*t+1]-h1f);
              hw[t] = (int)((uint32_t)h0 | ((uint32_t)h1 << 16));
              lw[t] = (int)((uint32_t)l0 | ((uint32_t)l1 << 16));
            }
            *(ivec4*)(smem +    0 + base) = hw;
            *(ivec4*)(smem + 8192 + base) = lw;
          }
          {
            int gr = min(n0 + row, N - 1);
            float rn = rnorm[gr];
            const float* s0 = xf + (size_t)gr * DIM + k0 + kg * 8;
            float4 a0 = *(const float4*)s0, a1 = *(const float4*)(s0 + 4);
            float vv[8] = {a0.x*rn,a0.y*rn,a0.z*rn,a0.w*rn,a1.x*rn,a1.y*rn,a1.z*rn,a1.w*rn};
            ivec4 hw, lw;
            #pragma unroll
            for (int t = 0; t < 4; ++t) {
              ushort_t h0 = bf16_rne(vv[2*t]), h1 = bf16_rne(vv[2*t+1]);
              float h0f = __builtin_bit_cast(float, (uint32_t)h0 << 16);
              float h1f = __builtin_bit_cast(float, (uint32_t)h1 << 16);
              ushort_t l0 = bf16_rne(vv[2*t]-h0f), l1 = bf16_rne(vv[2*t+1]-h1f);
              hw[t] = (int)((uint32_t)h0 | ((uint32_t)h1 << 16));
              lw[t] = (int)((uint32_t)l0 | ((uint32_t)l1 << 16));
            }
            *(ivec4*)(smem + 16384 + base) = hw;
            *(ivec4*)(smem + 24576 + base) = lw;
          }
        }
      }
      __syncthreads();  // drains global_load_lds (compiler emits vmcnt(0))

      bvec8 Ah[4], Al[4], Bh[4], Bl[4];
      #pragma unroll
      for (int i = 0; i < 4; ++i) {
        Ah[i] = __builtin_bit_cast(bvec8, *(const ivec4*)(smem +     0 + (wm*4 + i) * 1024 + l * 16));
        Al[i] = __builtin_bit_cast(bvec8, *(const ivec4*)(smem +  8192 + (wm*4 + i) * 1024 + l * 16));
        Bh[i] = __builtin_bit_cast(bvec8, *(const ivec4*)(smem + 16384 + (wn*4 + i) * 1024 + l * 16));
        Bl[i] = __builtin_bit_cast(bvec8, *(const ivec4*)(smem + 24576 + (wn*4 + i) * 1024 + l * 16));
      }
      #pragma unroll
      for (int i = 0; i < 4; ++i)
        #pragma unroll
        for (int j = 0; j < 4; ++j) {
          acc[i][j] = __builtin_amdgcn_mfma_f32_16x16x32_bf16(Ah[i], Bh[j], acc[i][j], 0, 0, 0);
          acc[i][j] = __builtin_amdgcn_mfma_f32_16x16x32_bf16(Ah[i], Bl[j], acc[i][j], 0, 0, 0);
          acc[i][j] = __builtin_amdgcn_mfma_f32_16x16x32_bf16(Al[i], Bh[j], acc[i][j], 0, 0, 0);
        }
      __syncthreads();
    }

    // fold tile into per-lane top-2 per owned query row
    #pragma unroll
    for (int j = 0; j < 4; ++j) {
      int n = n0 + wn * 64 + j * 16 + lrow;
      if (n < nEnd) {
        #pragma unroll
        for (int i = 0; i < 4; ++i)
          #pragma unroll
          for (int r = 0; r < 4; ++r) {
            float v = acc[i][j][r];
            int s = i * 4 + r;
            if (v > B1[s]) { B2[s] = B1[s]; I2[s] = I1[s]; B1[s] = v; I1[s] = n; }
            else if (v > B2[s]) { B2[s] = v; I2[s] = n; }
          }
      }
    }
  }

  // cross-lane top-2 merge over the 16 lanes sharing each query row
  #pragma unroll
  for (int s = 0; s < 16; ++s) {
    float b1 = B1[s], b2 = B2[s]; int i1 = I1[s], i2 = I2[s];
    #pragma unroll
    for (int off = 1; off < 16; off <<= 1) {
      float ob1 = __shfl_xor(b1, off, 64); int oi1 = __shfl_xor(i1, off, 64);
      float ob2 = __shfl_xor(b2, off, 64); int oi2 = __shfl_xor(i2, off, 64);
      bool take = (ob1 > b1) || (ob1 == b1 && oi1 < i1);
      float n1 = take ? ob1 : b1;  int n1i = take ? oi1 : i1;
      float c  = take ? b1  : ob1; int ci  = take ? i1  : oi1;  // loser of tops
      float ws = take ? ob2 : b2;  int wsi = take ? oi2 : i2;   // winner's 2nd
      bool s2 = (c > ws) || (c == ws && ci < wsi);
      b1 = n1; i1 = n1i;
      b2 = s2 ? c : ws; i2 = s2 ? ci : wsi;
    }
    if (lrow == 0) {
      int m = m0 + wm * 64 + (s >> 2) * 16 + (l >> 4) * 4 + (s & 3);
      size_t o = (((size_t)m * NSPLIT + split) * 2 + wn) * 2;  // per-wn slot (race fix)
      pval2[o] = b1; pval2[o + 1] = b2;
      pidx2[o] = i1; pidx2[o + 1] = i2;
    }
  }
}

// ---------- finalize: exact f32 rescore of near-max candidates, one-hot ----------
__global__ __launch_bounds__(256) void finalize_kernel(
    const float* __restrict__ pval2, const int* __restrict__ pidx2,
    const float* __restrict__ qf, const float* __restrict__ xf,
    const float* __restrict__ rnorm, const int* __restrict__ y,
    int* __restrict__ out) {
  int m = blockIdx.x;
  int tid = threadIdx.x, l = tid & 63, w = tid >> 6;
  __shared__ float sv[256]; __shared__ int si[256];
  __shared__ float swm[4];
  __shared__ float swv[4]; __shared__ int swi[4];
  __shared__ int s_label;
  sv[tid] = pval2[(size_t)m * 256 + tid];
  si[tid] = pidx2[(size_t)m * 256 + tid];
  __syncthreads();
  float v = sv[tid];
  #pragma unroll
  for (int off = 1; off < 64; off <<= 1) v = fmaxf(v, __shfl_xor(v, off, 64));
  if (l == 0) swm[w] = v;
  __syncthreads();
  float svmax = fmaxf(fmaxf(swm[0], swm[1]), fmaxf(swm[2], swm[3]));
  float thresh = svmax - MARGIN;
  float bestv = -FLT_MAX; int besti = 0x7fffffff;
  for (int cc = 0; cc < 64; ++cc) {
    int c = w * 64 + cc;
    float av = sv[c]; int idx = si[c];
    if (av < thresh) continue;  // wave-uniform branch
    const float4* qp = (const float4*)(qf + (size_t)m * DIM);
    const float4* xp = (const float4*)(xf + (size_t)idx * DIM);
    float s = 0.f;
    #pragma unroll
    for (int t = 0; t < 2; ++t) {
      float4 qa = qp[l * 2 + t], xa = xp[l * 2 + t];
      s += qa.x*xa.x + qa.y*xa.y + qa.z*xa.z + qa.w*xa.w;
    }
    #pragma unroll
    for (int off = 1; off < 64; off <<= 1) s += __shfl_xor(s, off, 64);
    float ev = s * rnorm[idx];
    if (ev > bestv || (ev == bestv && idx < besti)) { bestv = ev; besti = idx; }
  }
  if (l == 0) { swv[w] = bestv; swi[w] = besti; }
  __syncthreads();
  if (tid == 0) {
    float bv = swv[0]; int bi = swi[0];
    #pragma unroll
    for (int k = 1; k < 4; ++k)
      if (swv[k] > bv || (swv[k] == bv && swi[k] < bi)) { bv = swv[k]; bi = swi[k]; }
    s_label = y[bi];
  }
  __syncthreads();
  int label = s_label;
  for (int c = tid; c < NUM_CLASSES; c += 256)
    out[(size_t)m * NUM_CLASSES + c] = (c == label) ? 1 : 0;
}

extern "C" void kernel_launch(void* const* d_in, const int* in_sizes, int n_in,
                              void* d_out, int out_size, void* d_ws, size_t ws_size,
                              hipStream_t stream) {
  const float* x = (const float*)d_in[0];   // [N, 512]
  const int*   y = (const int*)d_in[1];     // [N]
  const float* q = (const float*)d_in[2];   // [M, 512]
  int N = in_sizes[0] / DIM;                // 100000
  int M = in_sizes[2] / DIM;                // 2048
  int* out = (int*)d_out;

  // workspace layout
  size_t off = 0;
  float* rnorm = (float*)((char*)d_ws + off); off += (((size_t)N * 4 + 1023) / 1024) * 1024;
  float* pval2 = (float*)((char*)d_ws + off); off += (size_t)M * NSPLIT * 4 * 4;
  int*   pidx2 = (int*)  ((char*)d_ws + off); off += (size_t)M * NSPLIT * 4 * 4;
  ushort_t* qh = (ushort_t*)((char*)d_ws + off); off += (size_t)M * DIM * 2;
  ushort_t* ql = (ushort_t*)((char*)d_ws + off); off += (size_t)M * DIM * 2;
  ushort_t* xh = (ushort_t*)((char*)d_ws + off); off += (size_t)N * DIM * 2;
  ushort_t* xl = (ushort_t*)((char*)d_ws + off); off += (size_t)N * DIM * 2;
  bool pre = (ws_size >= off);

  int nPerSplit = (N + NSPLIT - 1) / NSPLIT;  // 1563
  dim3 grid(NSPLIT, M / BM);                  // same split -> same XCD (id%8 = split%8)

  if (pre) {
    prep_split<<<(N + 3) / 4, 256, 0, stream>>>(x, rnorm, xh, xl, N, 1);
    prep_split<<<(M + 3) / 4, 256, 0, stream>>>(q, nullptr, qh, ql, M, 0);
    nn_mfma<true><<<grid, 256, 0, stream>>>(qh, ql, xh, xl, nullptr, nullptr,
                                            rnorm, pval2, pidx2, N, nPerSplit);
  } else {
    prep_split<<<(N + 3) / 4, 256, 0, stream>>>(x, rnorm, nullptr, nullptr, N, 1);
    nn_mfma<false><<<grid, 256, 0, stream>>>(nullptr, nullptr, nullptr, nullptr,
                                             q, x, rnorm, pval2, pidx2, N, nPerSplit);
  }
  finalize_kernel<<<M, 256, 0, stream>>>(pval2, pidx2, q, x, rnorm, y, out);
}